// Round 5
// baseline (263.151 us; speedup 1.0000x reference)
//
#include <hip/hip_runtime.h>

// CompactPiecewiseLinearEmbeddings: out[n,f,:] = C[f][k] + t*(C[f][k+1]-C[f][k])
// where k = #{j in [1,47] : edges[f][j] <= x[n,f]}, t = (x - edges[f][k]) / width[f][k],
// C[f][j] = bias[f] + sum_{b<j} W[f][b][:]   (sorted boundaries => h = [1..1, t, 0..0])
//
// R9: global-gather + linear write sweep. R5-R8 (occupancy, ILP, store line
// density, burst width) all null at ~161-170us => the invariant defects are
// (a) the temporal write pattern (every FT<256 layout assembles each 8KB
// output row from 8 blocks on different XCDs; L2 dirty-eviction streams to
// DRAM are 64-way strided interleaves) and (b) LDS staging redundancy.
// Tables are only ~550KB total and L2-resident per XCD, so: kernel1 builds
// cumC[f][0..48][8] and (r,-e*r)[f][j] in d_ws ONCE (4 blocks); kernel2 has
// NO LDS, NO barriers: 512-thread blocks, lane=(h,f)=(tid&1,tid>>1); each
// block-iter writes ONE full 8KB output row contiguously, consecutive iters
// consecutive rows => each block sweeps a 128KB linear region like the 6.7
// TB/s harness fill. Grid 1024 = exactly 4 blocks/CU @ (512,8), 32 w/CU.
// Gathers (e:16B + ra:8B + C:2x16B per half-task = 470MB) hit XCD-local L2
// at ~34TB/s, hidden under the write stream.

#define NN 16384
#define FF 256
#define BB 48
#define DD 8

#define CW_FLOATS (FF * (BB + 1) * DD)   // 100352 floats: cumC table
#define RA_FLOATS (FF * 2 * BB)          // 24576 floats: (r, -e*r) pairs

// ---------------- kernel 1: build tables into workspace ----------------
__global__ __launch_bounds__(512, 4)
void cple_tables(const float* __restrict__ Edg,
                 const float* __restrict__ Wid,
                 const float* __restrict__ W,
                 const float* __restrict__ Bias,
                 float* __restrict__ ws)
{
    const int tg = blockIdx.x * 512 + threadIdx.x;   // 0..2047
    const int f = tg >> 3, d = tg & 7;
    float* CW = ws;
    float* RA = ws + CW_FLOATS;

    // cumulative prefix: C[f][j][d] = bias[f][d] + sum_{b<j} W[f][b][d]
    float acc = Bias[(size_t)f * DD + d];
    float* cf = CW + (size_t)f * ((BB + 1) * DD) + d;
    cf[0] = acc;
    const float* wf = W + (size_t)f * BB * DD + d;
    #pragma unroll 8
    for (int b = 0; b < BB; ++b) {
        acc += wf[b * DD];
        cf[(b + 1) * DD] = acc;
    }

    // (r, -e*r) pairs, one thread per feature
    if (d == 0) {
        const float* ef = Edg + (size_t)f * BB;
        const float* vf = Wid + (size_t)f * BB;
        float2* raf = (float2*)(RA + (size_t)f * (2 * BB));
        #pragma unroll 8
        for (int j = 0; j < BB; ++j) {
            float r = 1.0f / vf[j];
            raf[j] = make_float2(r, -ef[j] * r);
        }
    }
}

// ---------------- kernel 2: linear-sweep main kernel ----------------
#define ROWS_PB 16          // rows per block; grid = NN/ROWS_PB = 1024 = 4/CU

__global__ __launch_bounds__(512, 8)
void cple_main(const float* __restrict__ X,
               const float* __restrict__ Edg,
               const float* __restrict__ ws,
               float* __restrict__ Out)
{
    const int tid = threadIdx.x;
    const int h   = tid & 1;          // d-half: d in [4h, 4h+4)
    const int f   = tid >> 1;         // 0..255, fixed per thread
    const int row0 = blockIdx.x * ROWS_PB;

    const float* CW = ws;
    const float* RA = ws + CW_FLOATS;

    const float* eF  = Edg + (size_t)f * BB;
    const float* raF = RA + (size_t)f * (2 * BB);
    const float* cF  = CW + (size_t)f * ((BB + 1) * DD) + h * 4;
    const float* xp  = X + f;
    float* op = Out + (size_t)f * DD + h * 4;

    // coarse search level -> registers (11 loads from L2-hot edges)
    float c4[11];
    #pragma unroll
    for (int m = 0; m < 11; ++m) c4[m] = eF[4 * (m + 1)];

    float xn = xp[(size_t)row0 * FF];

    #pragma unroll
    for (int i = 0; i < ROWS_PB; ++i) {
        const int n = row0 + i;
        float xc = xn;
        if (i < ROWS_PB - 1)   // prefetch next row's x (dense 128B span/wave)
            xn = xp[(size_t)(n + 1) * FF];

        // coarse: g = #{m: x >= E[4m+4]}, k4 = 4g (pure VALU, registers)
        int g = 0;
        #pragma unroll
        for (int m = 0; m < 11; ++m) g += (xc >= c4[m]) ? 1 : 0;
        const int k4 = g * 4;

        // fine: one aligned 16B load of E[k4..k4+3], count 3
        float4 e = *(const float4*)(eF + k4);
        const int k = k4 + (xc >= e.y) + (xc >= e.z) + (xc >= e.w);

        // gather from L2: (r,-e*r) 8B + C[k],C[k+1] half-d 2x16B
        float2 ra = *(const float2*)(raF + 2 * k);
        const float* cK = cF + k * DD;
        float4 lo = *(const float4*)(cK);
        float4 hi = *(const float4*)(cK + DD);

        float t = fmaf(xc, ra.x, ra.y);

        float4 o;
        o.x = fmaf(t, hi.x - lo.x, lo.x);
        o.y = fmaf(t, hi.y - lo.y, lo.y);
        o.z = fmaf(t, hi.z - lo.z, lo.z);
        o.w = fmaf(t, hi.w - lo.w, lo.w);

        // block writes one FULL 8KB row contiguously per iter; consecutive
        // iters -> consecutive rows (128KB linear sweep per block)
        *(float4*)(op + (size_t)n * (FF * DD)) = o;
    }
}

extern "C" void kernel_launch(void* const* d_in, const int* in_sizes, int n_in,
                              void* d_out, int out_size, void* d_ws, size_t ws_size,
                              hipStream_t stream) {
    const float* x     = (const float*)d_in[0];
    const float* edges = (const float*)d_in[1];
    const float* width = (const float*)d_in[2];
    const float* W     = (const float*)d_in[3];
    const float* b     = (const float*)d_in[4];
    float* out = (float*)d_out;
    float* ws  = (float*)d_ws;   // needs (100352 + 24576) * 4 B ~= 500 KB

    cple_tables<<<dim3(4), dim3(512), 0, stream>>>(edges, width, W, b, ws);
    cple_main<<<dim3(NN / ROWS_PB), dim3(512), 0, stream>>>(x, edges, ws, out);
}

// Round 6
// 172.043 us; speedup vs baseline: 1.5296x; 1.5296x over previous
//
#include <hip/hip_runtime.h>

// CompactPiecewiseLinearEmbeddings: out[n,f,:] = C[f][k] + t*(C[f][k+1]-C[f][k])
// where k = #{j in [1,47] : edges[f][j] <= x[n,f]}, t = (x - edges[f][k]) / width[f][k],
// C[f][j] = bias[f] + sum_{b<j} W[f][b][:]   (sorted boundaries => h = [1..1, t, 0..0])
//
// R10: register-resident edge scan. R9 (global gather) showed L2 gathers are
// 2x worse than LDS (127us, 64 uncoalesced L2 reqs/instr, 600cy chains) and
// that 2-launch structures cost ~40us of gaps -- revert to single-launch LDS.
// The last untested subsystem of the ~stable-80us LDS family is the per-task
// DEPENDENT chain: coarse(VALU) -> fine LDS b128 -> k -> gather LDS round =
// two serial ~120cy LDS rounds, pipelinable only to the VGPR cap. Fix: hold
// ALL 47 interior edges in registers (compile-time indices only, no scratch)
// and compute k = sum_j (x >= E[j]) as a flat 47-cmp VALU scan (94 instr/
// wave-iter; VALU floor ~10us, hidden under the 21us store stream). Leaves
// exactly ONE LDS round per task (ra b64 + 2x b128 C-gather). Budget: ~75
// VGPR => FT=16, 512-thr blocks, launch_bounds(512,6): VGPR cap ~84, 3
// blocks/CU (105KB LDS, 24 waves = 75% occ -- R5/R6 proved occupancy non-
// binding). Stores: 512B contiguous per 32-lane group (R7/R8: geometry null).

#define NN 16384
#define FF 256
#define BB 48
#define DD 8

#define FT 16              // features per block
#define NT 512             // threads per block
#define NSPLIT 64          // n-splits
#define NPB (NN / NSPLIT)  // 256 rows per block
#define RPI 16             // rows per iter (NT / (FT*2))
#define ITERS (NPB / RPI)  // 16

#define ESTR 52            // sE stride (floats): 16B-mult
#define RASTR 100          // sRA stride (floats): 8B-mult
#define CSTR 396           // sC stride (floats): 16B-mult

__global__ __launch_bounds__(NT, 6)
void cple_kernel(const float* __restrict__ X,
                 const float* __restrict__ Edg,
                 const float* __restrict__ Wid,
                 const float* __restrict__ W,
                 const float* __restrict__ Bias,
                 float* __restrict__ Out)
{
    __shared__ float sE [FT * ESTR];   // edges [f][j=0..47]        (3.3 KB)
    __shared__ float sRA[FT * RASTR];  // [f][j] -> (r, -e*r) pairs (6.4 KB)
    __shared__ float sC [FT * CSTR];   // cum W + bias [f][j][d]    (25.3 KB)

    const int tid = threadIdx.x;
    const int f0  = blockIdx.x * FT;
    const int ns  = blockIdx.y;

    // --- stage edges [f][0..47] (192 float4) ---
    if (tid < FT * BB / 4) {
        const float4* E4 = (const float4*)(Edg + (size_t)f0 * BB);
        float4 v = E4[tid];
        int f = tid / 12, j4 = tid % 12;
        *(float4*)&sE[f * ESTR + j4 * 4] = v;
    }
    // --- stage (r, -e*r) pairs (768 elems) ---
    for (int idx = tid; idx < FT * BB; idx += NT) {
        int f = idx / BB, j = idx - f * BB;
        float e = Edg[(size_t)f0 * BB + idx];
        float w = Wid[(size_t)f0 * BB + idx];
        float r = 1.0f / w;
        sRA[f * RASTR + 2 * j]     = r;
        sRA[f * RASTR + 2 * j + 1] = -e * r;
    }
    // --- stage W tile into sC at [f][b+1][d] (1536 float4, 3 per thread) ---
    {
        const float4* Wt4 = (const float4*)(W + (size_t)f0 * BB * DD);
        #pragma unroll
        for (int q = 0; q < 3; ++q) {
            int idx4 = tid + q * NT;
            float4 v = Wt4[idx4];
            int idx = idx4 * 4;
            int f   = idx / (BB * DD);
            int rem = idx - f * (BB * DD);
            *(float4*)&sC[f * CSTR + DD + rem] = v;
        }
    }

    // --- main-loop lane mapping: 32 lanes per n-row (16 f x 2 d-halves) ---
    const int h   = tid & 1;                  // d-half: d in [4h, 4h+4)
    const int f_l = (tid >> 1) & 15;          // feature within tile
    const int n_l = tid >> 5;                 // row within iter-slab (0..15)

    // --- issue first x load before the barrier (hide cold-HBM latency) ---
    const float* xp = X + (f0 + f_l);
    float* op = Out + (size_t)(f0 + f_l) * DD + h * 4;

    const int nbase = ns * NPB + n_l;
    float xn = xp[(size_t)nbase * FF];

    __syncthreads();

    // --- prefix scan: C[f][j][d] = bias + sum_{b<j} W[f][b][d] (reg-chunked) ---
    if (tid < FT * DD) {
        int f = tid >> 3, d = tid & 7;
        float* c = &sC[f * CSTR + d];
        float acc = Bias[(size_t)(f0 + f) * DD + d];
        c[0] = acc;
        #pragma unroll
        for (int ch = 0; ch < 3; ++ch) {
            float w[16];
            #pragma unroll
            for (int j = 0; j < 16; ++j) w[j] = c[(ch * 16 + j + 1) * DD];
            #pragma unroll
            for (int j = 0; j < 16; ++j) { acc += w[j]; c[(ch * 16 + j + 1) * DD] = acc; }
        }
    }

    // --- ALL 47 interior edges -> registers (compile-time indices only) ---
    const float* eF  = &sE [f_l * ESTR];
    const float* raF = &sRA[f_l * RASTR];
    const float* cF  = &sC [f_l * CSTR] + h * 4;
    float er[47];
    #pragma unroll
    for (int j = 0; j < 47; ++j) er[j] = eF[j + 1];

    __syncthreads();

    // --- main loop: 16 rows/iter, 16 iters; ONE LDS round per task ---
    #pragma unroll
    for (int i = 0; i < ITERS; ++i) {
        int n = nbase + i * RPI;
        float xc = xn;
        if (i < ITERS - 1)   // prefetch next row's x
            xn = xp[(size_t)(n + RPI) * FF];

        // flat register scan: k = #{j in [1,47]: x >= E[j]} (pure VALU)
        int k = 0;
        #pragma unroll
        for (int j = 0; j < 47; ++j) k += (xc >= er[j]) ? 1 : 0;

        // single LDS gather round: (r,-e*r) b64 + C[k],C[k+1] half-d 2x b128
        float2 ra = *(const float2*)(raF + 2 * k);
        const float* cK = cF + k * DD;
        float4 lo = *(const float4*)(cK);
        float4 hi = *(const float4*)(cK + DD);

        float t = fmaf(xc, ra.x, ra.y);

        float4 o;
        o.x = fmaf(t, hi.x - lo.x, lo.x);
        o.y = fmaf(t, hi.y - lo.y, lo.y);
        o.z = fmaf(t, hi.z - lo.z, lo.z);
        o.w = fmaf(t, hi.w - lo.w, lo.w);

        // 32-lane group covers 512B contiguous of row n
        *(float4*)(op + (size_t)n * (FF * DD)) = o;
    }
}

extern "C" void kernel_launch(void* const* d_in, const int* in_sizes, int n_in,
                              void* d_out, int out_size, void* d_ws, size_t ws_size,
                              hipStream_t stream) {
    const float* x     = (const float*)d_in[0];
    const float* edges = (const float*)d_in[1];
    const float* width = (const float*)d_in[2];
    const float* W     = (const float*)d_in[3];
    const float* b     = (const float*)d_in[4];
    float* out = (float*)d_out;

    dim3 grid(FF / FT, NSPLIT);
    cple_kernel<<<grid, NT, 0, stream>>>(x, edges, width, W, b, out);
}

// Round 7
// 161.674 us; speedup vs baseline: 1.6277x; 1.0641x over previous
//
#include <hip/hip_runtime.h>

// CompactPiecewiseLinearEmbeddings: out[n,f,:] = C[f][k] + t*(C[f][k+1]-C[f][k])
// where k = #{j in [1,47] : edges[f][j] <= x[n,f]}, t = (x - edges[f][k]) / width[f][k],
// C[f][j] = bias[f] + sum_{b<j} W[f][b][:]   (sorted boundaries => h = [1..1, t, 0..0])
//
// R11 = R8 verbatim (best measured: 161.1us). R9's visible cple_main (127us)
// calibrated the harness floor: poison-fill ~80us + launch gaps ~50us =
// ~130us fixed; the LDS-family kernels are actually ~30-42us (NOT ~78us),
// vs a 150MB traffic roofline of ~24us. R8 is the fastest variant (~31us
// kernel, ~77% of traffic bound): FT=32 + 1024-thread block, whole wave on
// one output row (1KB dense stores), LDS 68.5KB => exactly 2 blocks/CU,
// grid 512 = 2/CU, 32 waves/CU, two-level search (coarse in regs, fine b128)
// + one LDS gather round. Remaining headroom <= 7us (< fill jitter); if this
// reproduces <= 164us the session declares roofline.

#define NN 16384
#define FF 256
#define BB 48
#define DD 8

#define FT 32              // features per block
#define NT 1024            // threads per block
#define NSPLIT 64          // n-splits
#define NPB (NN / NSPLIT)  // 256 rows per block
#define RPI 16             // rows per iter (NT/64)
#define ITERS (NPB / RPI)  // 16

#define ESTR 52            // sE stride: 16B-mult
#define RASTR 100          // sRA stride (floats)
#define CSTR 396           // sC stride: 16B-mult

__global__ __launch_bounds__(NT, 8)
void cple_kernel(const float* __restrict__ X,
                 const float* __restrict__ Edg,
                 const float* __restrict__ Wid,
                 const float* __restrict__ W,
                 const float* __restrict__ Bias,
                 float* __restrict__ Out)
{
    __shared__ float sE [FT * ESTR];   // edges [f][j=0..47]        (6.5 KB)
    __shared__ float sRA[FT * RASTR];  // [f][j] -> (r, -e*r) pairs (12.5 KB)
    __shared__ float sC [FT * CSTR];   // cum W + bias [f][j][d]    (49.5 KB)

    const int tid = threadIdx.x;
    const int f0  = blockIdx.x * FT;
    const int ns  = blockIdx.y;

    // --- stage edges [f][0..47] (384 float4) ---
    if (tid < FT * BB / 4) {
        const float4* E4 = (const float4*)(Edg + (size_t)f0 * BB);
        float4 v = E4[tid];
        int f = tid / 12, j4 = tid % 12;
        *(float4*)&sE[f * ESTR + j4 * 4] = v;
    }
    // --- stage (r, -e*r) pairs (1536 elems) ---
    for (int idx = tid; idx < FT * BB; idx += NT) {
        int f = idx / BB, j = idx - f * BB;
        float e = Edg[(size_t)f0 * BB + idx];
        float w = Wid[(size_t)f0 * BB + idx];
        float r = 1.0f / w;
        sRA[f * RASTR + 2 * j]     = r;
        sRA[f * RASTR + 2 * j + 1] = -e * r;
    }
    // --- stage W tile into sC at [f][b+1][d] (3072 float4, 3 per thread) ---
    {
        const float4* Wt4 = (const float4*)(W + (size_t)f0 * BB * DD);
        #pragma unroll
        for (int q = 0; q < 3; ++q) {
            int idx4 = tid + q * NT;
            float4 v = Wt4[idx4];
            int idx = idx4 * 4;
            int f   = idx / (BB * DD);
            int rem = idx - f * (BB * DD);
            *(float4*)&sC[f * CSTR + DD + rem] = v;
        }
    }

    // --- main-loop lane mapping: whole wave on ONE n-row ---
    const int h   = tid & 1;                  // d-half: d in [4h, 4h+4)
    const int f_l = (tid >> 1) & 31;          // feature within tile
    const int w_l = tid >> 6;                 // wave id = row within slab (0..15)

    // --- issue first x load before the barrier (hide cold-HBM latency) ---
    const float* xp = X + (f0 + f_l);
    float* op = Out + (size_t)(f0 + f_l) * DD + h * 4;

    const int nbase = ns * NPB + w_l;
    float xn = xp[(size_t)nbase * FF];

    __syncthreads();

    // --- coarse search level -> registers ---
    const float* eF  = &sE [f_l * ESTR];
    const float* raF = &sRA[f_l * RASTR];
    const float* cF  = &sC [f_l * CSTR] + h * 4;
    float c4[11];
    #pragma unroll
    for (int m = 0; m < 11; ++m) c4[m] = eF[4 * (m + 1)];

    // --- prefix scan: C[f][j][d] = bias + sum_{b<j} W[f][b][d] (reg-chunked) ---
    if (tid < FT * DD) {
        int f = tid >> 3, d = tid & 7;
        float* c = &sC[f * CSTR + d];
        float acc = Bias[(size_t)(f0 + f) * DD + d];
        c[0] = acc;
        #pragma unroll
        for (int ch = 0; ch < 3; ++ch) {
            float w[16];
            #pragma unroll
            for (int j = 0; j < 16; ++j) w[j] = c[(ch * 16 + j + 1) * DD];
            #pragma unroll
            for (int j = 0; j < 16; ++j) { acc += w[j]; c[(ch * 16 + j + 1) * DD] = acc; }
        }
    }
    __syncthreads();

    // --- main loop: 16 rows/iter (1 row per wave), 16 iters ---
    #pragma unroll
    for (int i = 0; i < ITERS; ++i) {
        int n = nbase + i * RPI;
        float xc = xn;
        if (i < ITERS - 1)   // prefetch next row's x (dense 128B span per wave)
            xn = xp[(size_t)(n + RPI) * FF];

        // coarse: group g = #{m: x >= E[4m+4]}, k4 = 4g (pure VALU, registers)
        int g = 0;
        #pragma unroll
        for (int m = 0; m < 11; ++m) g += (xc >= c4[m]) ? 1 : 0;
        int k4 = g * 4;

        // fine: one aligned b128 of E[k4..k4+3], count 3
        float4 e = *(const float4*)(eF + k4);
        int k = k4 + (xc >= e.y) + (xc >= e.z) + (xc >= e.w);

        // gather: (r,-e*r) b64 + C[k],C[k+1] half-d, 2x b128 per lane
        float2 ra = *(const float2*)(raF + 2 * k);
        const float* cK = cF + k * DD;
        float4 lo = *(const float4*)(cK);
        float4 hi = *(const float4*)(cK + DD);

        float t = fmaf(xc, ra.x, ra.y);

        float4 o;
        o.x = fmaf(t, hi.x - lo.x, lo.x);
        o.y = fmaf(t, hi.y - lo.y, lo.y);
        o.z = fmaf(t, hi.z - lo.z, lo.z);
        o.w = fmaf(t, hi.w - lo.w, lo.w);

        // dense store: wave covers 1024B contiguous of row n
        *(float4*)(op + (size_t)n * (FF * DD)) = o;
    }
}

extern "C" void kernel_launch(void* const* d_in, const int* in_sizes, int n_in,
                              void* d_out, int out_size, void* d_ws, size_t ws_size,
                              hipStream_t stream) {
    const float* x     = (const float*)d_in[0];
    const float* edges = (const float*)d_in[1];
    const float* width = (const float*)d_in[2];
    const float* W     = (const float*)d_in[3];
    const float* b     = (const float*)d_in[4];
    float* out = (float*)d_out;

    dim3 grid(FF / FT, NSPLIT);
    cple_kernel<<<grid, NT, 0, stream>>>(x, edges, width, W, b, out);
}